// Round 15
// baseline (33.139 us; speedup 1.0000x reference)
//
#include <hip/hip_runtime.h>
#include <hip/hip_bf16.h>

constexpr int Bc = 4, Nc = 16384, Mc = 4096, Kc = 32;
constexpr float EPSc = 1e-5f;
constexpr float L2E = 1.4426950408889634f;   // log2(e)

using bf16x8 = __attribute__((ext_vector_type(8))) short;   // 8 bf16 (4 VGPRs)
using f32x4  = __attribute__((ext_vector_type(4))) float;   // 4 fp32 (native vec)

// HW bf16 converts (v_cvt_pk_bf16_f32, RNE)
__device__ inline short f2bf(float x) {
    union { __hip_bfloat16 h; short s; } cv;
    cv.h = __float2bfloat16(x);
    return cv.s;
}
__device__ inline unsigned pk2(float lo, float hi) {   // low16=bf16(lo), high16=bf16(hi)
    union { __hip_bfloat162 h2; unsigned u; } cv;
    cv.h2 = __float22bfloat162_rn(make_float2(lo, hi));
    return cv.u;
}

// ---------------------------------------------------------------------------
// pt_enc (MFMA): Sfa[n][c] = pack( hi = bf16((f_bn + dot(x_n,w_c))*log2e),
//                                  lo = bf16(a_bn + dot(x_n,w_c)) )
// Batch->XCD-pair pinned swizzle identical to pt_gr7. Single-use streaming
// inputs (feats, xyz) via nontemporal loads (native-vector type) so they
// don't evict the Sfa write-lines from the pinned L2s before pt_gr7 reads.
// ---------------------------------------------------------------------------
__global__ __launch_bounds__(256) void pt_enc(
    const float* __restrict__ feats, const float* __restrict__ xyz,
    const float* __restrict__ Wf, const float* __restrict__ Wa,
    const float* __restrict__ Wx,
    const float* __restrict__ fg, const float* __restrict__ fb,
    const float* __restrict__ fm, const float* __restrict__ fv,
    const float* __restrict__ ag, const float* __restrict__ ab,
    const float* __restrict__ am, const float* __restrict__ av,
    const float* __restrict__ xg, const float* __restrict__ xb,
    const float* __restrict__ xm, const float* __restrict__ xv,
    unsigned* __restrict__ Sfa)
{
    __shared__ __align__(16) short WT[128][72];   // [col][k]
    __shared__ unsigned stile[4][16][68];         // transpose tile per wave
    __shared__ float  sx[64][3];                  // block's 64 points' xyz
    __shared__ float4 scw[64];                    // per-channel {w0,w1,w2,-}
    __shared__ float  bis[128];

    const int tid = threadIdx.x, lane = tid & 63, w = tid >> 6;
    const int row16 = lane & 15, kg = lane >> 4;
    // bijective XCD-pinning swizzle (matches pt_gr7): xcd=blk%8 -> batch (blk%8)>>1
    const int i = blockIdx.x;                     // 0..1023
    const int b = (i & 7) >> 1;
    const int j = ((i >> 3) << 1) | (i & 1);      // 0..255 tile within batch
    const long long row0 = ((long long)b * 256 + j) * 64;

    if (tid < 192)
        ((float*)sx)[tid] = __builtin_nontemporal_load(xyz + row0 * 3 + tid);
    if (tid < 64) {
        const float xs = xg[tid] * rsqrtf(xv[tid] + EPSc);
        scw[tid] = make_float4(Wx[tid] * xs, Wx[64 + tid] * xs,
                               Wx[128 + tid] * xs, 0.f);
    }
    if (tid < 128) {
        const int c = tid & 63;
        const float g  = (tid < 64) ? fg[c] : ag[c];
        const float v  = (tid < 64) ? fv[c] : av[c];
        const float bb = (tid < 64) ? fb[c] : ab[c];
        const float mm = (tid < 64) ? fm[c] : am[c];
        const float s = g * rsqrtf(v + EPSc);
        bis[tid] = (tid < 64) ? (bb - mm * s) * L2E : (bb - mm * s);
    }
    {   // WT staging: thread owns channel c = tid&63 for both planes
        const int c = tid & 63, k0 = tid >> 6;
        const float sf = fg[c] * rsqrtf(fv[c] + EPSc) * L2E;
        const float sa = ag[c] * rsqrtf(av[c] + EPSc);
#pragma unroll
        for (int it = 0; it < 16; ++it) {
            const int k = k0 + 4 * it;
            WT[c][k]      = f2bf(Wf[k * 64 + c] * sf);
            WT[64 + c][k] = f2bf(Wa[k * 64 + c] * sa);
        }
    }
    __syncthreads();

    bf16x8 bfr[8][2];
#pragma unroll
    for (int t = 0; t < 8; ++t)
#pragma unroll
        for (int h = 0; h < 2; ++h)
            bfr[t][h] = *(const bf16x8*)&WT[16 * t + row16][32 * h + kg * 8];

    const long long base = row0 + w * 16;
    const float* arow = feats + (base + row16) * 64 + kg * 8;
    // single-use stream: nontemporal via native vector type
    const f32x4 v0 = __builtin_nontemporal_load((const f32x4*)(arow + 0));
    const f32x4 v1 = __builtin_nontemporal_load((const f32x4*)(arow + 4));
    const f32x4 v2 = __builtin_nontemporal_load((const f32x4*)(arow + 32));
    const f32x4 v3 = __builtin_nontemporal_load((const f32x4*)(arow + 36));
    union { unsigned u[4]; bf16x8 v; } A0, A1;    // HW cvt_pk pairs
    A0.u[0] = pk2(v0[0], v0[1]); A0.u[1] = pk2(v0[2], v0[3]);
    A0.u[2] = pk2(v1[0], v1[1]); A0.u[3] = pk2(v1[2], v1[3]);
    A1.u[0] = pk2(v2[0], v2[1]); A1.u[1] = pk2(v2[2], v2[3]);
    A1.u[2] = pk2(v3[0], v3[1]); A1.u[3] = pk2(v3[2], v3[3]);

    f32x4 acc[8];
#pragma unroll
    for (int t = 0; t < 8; ++t) {
        f32x4 z = {0.f, 0.f, 0.f, 0.f};
        z = __builtin_amdgcn_mfma_f32_16x16x32_bf16(A0.v, bfr[t][0], z, 0, 0, 0);
        z = __builtin_amdgcn_mfma_f32_16x16x32_bf16(A1.v, bfr[t][1], z, 0, 0, 0);
        acc[t] = z;
    }

    // per-lane xyz-proj coeffs for this lane's 4 output cols
    float4 cwt[4];
#pragma unroll
    for (int t = 0; t < 4; ++t)
        cwt[t] = scw[16 * t + row16];

    const int lrow = w * 16 + kg * 4;
    // C/D layout: row=(lane>>4)*4+reg, col=lane&15 -> LDS tile -> coalesced
#pragma unroll
    for (int r = 0; r < 4; ++r) {
        const float x0 = sx[lrow + r][0], x1 = sx[lrow + r][1], x2 = sx[lrow + r][2];
#pragma unroll
        for (int t = 0; t < 4; ++t) {
            const int c = 16 * t + row16;
            const float px = fmaf(x0, cwt[t].x, fmaf(x1, cwt[t].y, x2 * cwt[t].z));
            // low16 = attn plane, high16 = feat plane (exp2 domain)
            stile[w][kg * 4 + r][c] = pk2(acc[t + 4][r] + bis[64 + c] + px,
                                          acc[t][r] + bis[c] + px * L2E);
        }
    }
    __syncthreads();
#pragma unroll
    for (int rr = 0; rr < 16; ++rr)
        Sfa[(base + rr) * 64 + lane] = stile[w][rr][lane];
}

// ---------------------------------------------------------------------------
// pt_gr7 (R13 structure): 512 thr = 8 waves, 2 groups/wave, 1024 blocks.
// readlane -> SGPR index -> SALU gather addressing; softmax shift-invariance.
// XCD-pinned swizzle. gidx loads nontemporal (single-use stream).
// ---------------------------------------------------------------------------
__global__ __launch_bounds__(512) void pt_gr7(
    const float* __restrict__ nxyz, const unsigned* __restrict__ Sfa,
    const float* __restrict__ Wr,
    const float* __restrict__ rg, const float* __restrict__ rb,
    const float* __restrict__ rm, const float* __restrict__ rv,
    const float* __restrict__ Wx,
    const float* __restrict__ xg, const float* __restrict__ xb,
    const float* __restrict__ xm, const float* __restrict__ xv,
    const int* __restrict__ gidx, const int* __restrict__ gcnt,
    float* __restrict__ out)
{
    __shared__ __align__(16) short WT[128][72];   // refine weights [col][k]
    __shared__ __align__(16) short snf[16][72];   // softmax outputs [group][ch]

    const int tid = threadIdx.x, lane = tid & 63, w = tid >> 6;
    const int row16 = lane & 15, kg = lane >> 4;
    // bijective XCD-pinning swizzle: xcd = blk%8 serves batch (blk%8)>>1
    const int i = blockIdx.x;                     // 0..1023
    const int b = (i & 7) >> 1;
    const int j = ((i >> 3) << 1) | (i & 1);      // 0..255
    const long long gbase = (long long)b * Mc + j * 16;

    // both groups' neighbor lists in one coalesced 64-int load (wave-local)
    const int nv = __builtin_nontemporal_load(gidx + (gbase + 2 * w) * 32 + lane);

    {   // WT staging: thread owns channel c = tid&127 (scale in registers)
        const int c = tid & 127, k0 = tid >> 7;
        const float sr = rg[c] * rsqrtf(rv[c] + EPSc);
#pragma unroll
        for (int it = 0; it < 16; ++it) {
            const int k = k0 + 4 * it;
            WT[c][k] = f2bf(Wr[k * 128 + c] * sr);
        }
    }

    // per-lane channel coeffs (channel = lane) + per-group constants
    const float xs = xg[lane] * rsqrtf(xv[lane] + EPSc);
    const float w0 = Wx[lane] * xs, w1 = Wx[64 + lane] * xs, w2 = Wx[128 + lane] * xs;
    const float P = xb[lane] - xm[lane] * xs;
    const float* nx = nxyz + (gbase + 2 * w) * 3;  // 6 floats = both groups
    const float QA = P - fmaf(nx[0], w0, fmaf(nx[1], w1, nx[2] * w2));
    const float QB = P - fmaf(nx[3], w0, fmaf(nx[4], w1, nx[5] * w2));

    const unsigned* sbase = Sfa + (long long)b * (Nc * 64) + lane;
    float ssA = 0.f, acA = 0.f, ssB = 0.f, acB = 0.f;
#pragma unroll
    for (int k = 0; k < Kc; ++k) {
        const int nA = __builtin_amdgcn_readlane(nv, k);        // SGPR index
        const int nB = __builtin_amdgcn_readlane(nv, 32 + k);
        const unsigned dA = sbase[nA << 6];        // SALU-addressed 256B gather
        const unsigned dB = sbase[nB << 6];
        // shift-invariance: u = exp2(hi) (Q cancels in the ratio)
        const float uA = __builtin_amdgcn_exp2f(__uint_as_float(dA & 0xffff0000u));
        const float uB = __builtin_amdgcn_exp2f(__uint_as_float(dB & 0xffff0000u));
        const float aA = __uint_as_float(dA << 16);
        const float aB = __uint_as_float(dB << 16);
        ssA += uA; acA = fmaf(uA, aA, acA);
        ssB += uB; acB = fmaf(uB, aB, acB);
    }
    snf[2 * w][lane]     = f2bf(fmaf(acA, __builtin_amdgcn_rcpf(ssA), QA));
    snf[2 * w + 1][lane] = f2bf(fmaf(acB, __builtin_amdgcn_rcpf(ssB), QB));
    __syncthreads();

    // refine MFMA: A = snf (16 rows), B = WT col-tile w
    const bf16x8 af0 = *(const bf16x8*)&snf[row16][kg * 8];
    const bf16x8 af1 = *(const bf16x8*)&snf[row16][32 + kg * 8];
    const bf16x8 bf0 = *(const bf16x8*)&WT[16 * w + row16][kg * 8];
    const bf16x8 bf1 = *(const bf16x8*)&WT[16 * w + row16][32 + kg * 8];
    f32x4 z = {0.f, 0.f, 0.f, 0.f};
    z = __builtin_amdgcn_mfma_f32_16x16x32_bf16(af0, bf0, z, 0, 0, 0);
    z = __builtin_amdgcn_mfma_f32_16x16x32_bf16(af1, bf1, z, 0, 0, 0);

    // epilogue: BN+ReLU+mask; per-lane channel cc fixed -> scale in registers
    const int4 c4 = *(const int4*)(gcnt + gbase + kg * 4);
    const int cc = 16 * w + row16;
    const float sr = rg[cc] * rsqrtf(rv[cc] + EPSc);
    const float bb = rb[cc] - rm[cc] * sr;
    float* orow = out + (gbase + kg * 4) * 128 + cc;
    __builtin_nontemporal_store(fmaxf(z[0] + bb, 0.f) * (c4.x > 0 ? 1.f : 0.f), orow);
    __builtin_nontemporal_store(fmaxf(z[1] + bb, 0.f) * (c4.y > 0 ? 1.f : 0.f), orow + 128);
    __builtin_nontemporal_store(fmaxf(z[2] + bb, 0.f) * (c4.z > 0 ? 1.f : 0.f), orow + 256);
    __builtin_nontemporal_store(fmaxf(z[3] + bb, 0.f) * (c4.w > 0 ? 1.f : 0.f), orow + 384);
}

extern "C" void kernel_launch(void* const* d_in, const int* in_sizes, int n_in,
                              void* d_out, int out_size, void* d_ws, size_t ws_size,
                              hipStream_t stream)
{
    const float* xyz  = (const float*)d_in[0];
    const float* nxyz = (const float*)d_in[1];
    const float* feats = (const float*)d_in[2];
    const float* Wf = (const float*)d_in[3];
    const float* fg = (const float*)d_in[4];
    const float* fb = (const float*)d_in[5];
    const float* fm = (const float*)d_in[6];
    const float* fv = (const float*)d_in[7];
    const float* Wa = (const float*)d_in[8];
    const float* ag = (const float*)d_in[9];
    const float* ab = (const float*)d_in[10];
    const float* am = (const float*)d_in[11];
    const float* av = (const float*)d_in[12];
    const float* Wx = (const float*)d_in[13];
    const float* xg = (const float*)d_in[14];
    const float* xb = (const float*)d_in[15];
    const float* xm = (const float*)d_in[16];
    const float* xv = (const float*)d_in[17];
    const float* Wr = (const float*)d_in[18];
    const float* rg = (const float*)d_in[19];
    const float* rb = (const float*)d_in[20];
    const float* rm = (const float*)d_in[21];
    const float* rv = (const float*)d_in[22];
    const int* gidx = (const int*)d_in[23];
    const int* gcnt = (const int*)d_in[24];
    float* out = (float*)d_out;

    unsigned* Sfa = (unsigned*)d_ws;   // B*N*64 dwords = 16 MiB packed bf16 pairs

    pt_enc<<<dim3(Bc * Nc / 64), dim3(256), 0, stream>>>(
        feats, xyz, Wf, Wa, Wx,
        fg, fb, fm, fv, ag, ab, am, av, xg, xb, xm, xv, Sfa);
    pt_gr7<<<dim3((Bc * Mc) / 16), dim3(512), 0, stream>>>(
        nxyz, Sfa, Wr, rg, rb, rm, rv, Wx, xg, xb, xm, xv,
        gidx, gcnt, out);
}

// Round 16
// 30.875 us; speedup vs baseline: 1.0733x; 1.0733x over previous
//
#include <hip/hip_runtime.h>
#include <hip/hip_bf16.h>

constexpr int Bc = 4, Nc = 16384, Mc = 4096, Kc = 32;
constexpr float EPSc = 1e-5f;
constexpr float L2E = 1.4426950408889634f;   // log2(e)

using bf16x8 = __attribute__((ext_vector_type(8))) short;   // 8 bf16 (4 VGPRs)
using f32x4  = __attribute__((ext_vector_type(4))) float;   // 4 fp32

// HW bf16 converts (v_cvt_pk_bf16_f32, RNE)
__device__ inline short f2bf(float x) {
    union { __hip_bfloat16 h; short s; } cv;
    cv.h = __float2bfloat16(x);
    return cv.s;
}
__device__ inline unsigned pk2(float lo, float hi) {   // low16=bf16(lo), high16=bf16(hi)
    union { __hip_bfloat162 h2; unsigned u; } cv;
    cv.h2 = __float22bfloat162_rn(make_float2(lo, hi));
    return cv.u;
}

// ---------------------------------------------------------------------------
// pt_enc (MFMA): Sfa[n][c] = pack( hi = bf16((f_bn + dot(x_n,w_c))*log2e),
//                                  lo = bf16(a_bn + dot(x_n,w_c)) )
// R13 structure (plain loads — R15's nontemporal regressed). Blocks >= 1024
// (4 extra) pre-bake WrT = bf16(Wr * refine-BN-scale) into ws instead, so
// pt_gr needs no per-block Wr staging (kernel boundary orders the two).
// ---------------------------------------------------------------------------
__global__ __launch_bounds__(256) void pt_enc(
    const float* __restrict__ feats, const float* __restrict__ xyz,
    const float* __restrict__ Wf, const float* __restrict__ Wa,
    const float* __restrict__ Wx,
    const float* __restrict__ fg, const float* __restrict__ fb,
    const float* __restrict__ fm, const float* __restrict__ fv,
    const float* __restrict__ ag, const float* __restrict__ ab,
    const float* __restrict__ am, const float* __restrict__ av,
    const float* __restrict__ xg, const float* __restrict__ xb,
    const float* __restrict__ xm, const float* __restrict__ xv,
    const float* __restrict__ Wr,
    const float* __restrict__ rg, const float* __restrict__ rv,
    unsigned* __restrict__ Sfa, short* __restrict__ WrT)
{
    const int tid = threadIdx.x;
    if (blockIdx.x >= 1024) {                     // WrT bake: 4 blocks
        const int idx = (blockIdx.x - 1024) * 256 + tid;   // 0..1023
        const int c = idx & 127, k0 = (idx >> 7) * 8;
        const float sr = rg[c] * rsqrtf(rv[c] + EPSc);
#pragma unroll
        for (int k = k0; k < k0 + 8; ++k)
            WrT[c * 64 + k] = f2bf(Wr[k * 128 + c] * sr);
        return;
    }

    __shared__ __align__(16) short WT[128][72];   // [col][k]
    __shared__ unsigned stile[4][16][68];         // transpose tile per wave
    __shared__ float  sx[64][3];                  // block's 64 points' xyz
    __shared__ float4 scw[64];                    // per-channel {w0,w1,w2,-}
    __shared__ float  bis[128];

    const int lane = tid & 63, w = tid >> 6;
    const int row16 = lane & 15, kg = lane >> 4;
    // bijective XCD-pinning swizzle (matches pt_gr): xcd=blk%8 -> batch (blk%8)>>1
    const int i = blockIdx.x;                     // 0..1023
    const int b = (i & 7) >> 1;
    const int j = ((i >> 3) << 1) | (i & 1);      // 0..255 tile within batch
    const long long row0 = ((long long)b * 256 + j) * 64;

    if (tid < 192) ((float*)sx)[tid] = xyz[row0 * 3 + tid];
    if (tid < 64) {
        const float xs = xg[tid] * rsqrtf(xv[tid] + EPSc);
        scw[tid] = make_float4(Wx[tid] * xs, Wx[64 + tid] * xs,
                               Wx[128 + tid] * xs, 0.f);
    }
    if (tid < 128) {
        const int c = tid & 63;
        const float g  = (tid < 64) ? fg[c] : ag[c];
        const float v  = (tid < 64) ? fv[c] : av[c];
        const float bb = (tid < 64) ? fb[c] : ab[c];
        const float mm = (tid < 64) ? fm[c] : am[c];
        const float s = g * rsqrtf(v + EPSc);
        bis[tid] = (tid < 64) ? (bb - mm * s) * L2E : (bb - mm * s);
    }
    {   // WT staging: thread owns channel c = tid&63 for both planes
        const int c = tid & 63, k0 = tid >> 6;
        const float sf = fg[c] * rsqrtf(fv[c] + EPSc) * L2E;
        const float sa = ag[c] * rsqrtf(av[c] + EPSc);
#pragma unroll
        for (int it = 0; it < 16; ++it) {
            const int k = k0 + 4 * it;
            WT[c][k]      = f2bf(Wf[k * 64 + c] * sf);
            WT[64 + c][k] = f2bf(Wa[k * 64 + c] * sa);
        }
    }
    __syncthreads();

    bf16x8 bfr[8][2];
#pragma unroll
    for (int t = 0; t < 8; ++t)
#pragma unroll
        for (int h = 0; h < 2; ++h)
            bfr[t][h] = *(const bf16x8*)&WT[16 * t + row16][32 * h + kg * 8];

    const long long base = row0 + w * 16;
    const float* arow = feats + (base + row16) * 64 + kg * 8;
    const float4 v0 = *(const float4*)(arow + 0);
    const float4 v1 = *(const float4*)(arow + 4);
    const float4 v2 = *(const float4*)(arow + 32);
    const float4 v3 = *(const float4*)(arow + 36);
    union { unsigned u[4]; bf16x8 v; } A0, A1;    // HW cvt_pk pairs
    A0.u[0] = pk2(v0.x, v0.y); A0.u[1] = pk2(v0.z, v0.w);
    A0.u[2] = pk2(v1.x, v1.y); A0.u[3] = pk2(v1.z, v1.w);
    A1.u[0] = pk2(v2.x, v2.y); A1.u[1] = pk2(v2.z, v2.w);
    A1.u[2] = pk2(v3.x, v3.y); A1.u[3] = pk2(v3.z, v3.w);

    f32x4 acc[8];
#pragma unroll
    for (int t = 0; t < 8; ++t) {
        f32x4 z = {0.f, 0.f, 0.f, 0.f};
        z = __builtin_amdgcn_mfma_f32_16x16x32_bf16(A0.v, bfr[t][0], z, 0, 0, 0);
        z = __builtin_amdgcn_mfma_f32_16x16x32_bf16(A1.v, bfr[t][1], z, 0, 0, 0);
        acc[t] = z;
    }

    // per-lane xyz-proj coeffs for this lane's 4 output cols
    float4 cwt[4];
#pragma unroll
    for (int t = 0; t < 4; ++t)
        cwt[t] = scw[16 * t + row16];

    const int lrow = w * 16 + kg * 4;
    // C/D layout: row=(lane>>4)*4+reg, col=lane&15 -> LDS tile -> coalesced
#pragma unroll
    for (int r = 0; r < 4; ++r) {
        const float x0 = sx[lrow + r][0], x1 = sx[lrow + r][1], x2 = sx[lrow + r][2];
#pragma unroll
        for (int t = 0; t < 4; ++t) {
            const int c = 16 * t + row16;
            const float px = fmaf(x0, cwt[t].x, fmaf(x1, cwt[t].y, x2 * cwt[t].z));
            // low16 = attn plane, high16 = feat plane (exp2 domain)
            stile[w][kg * 4 + r][c] = pk2(acc[t + 4][r] + bis[64 + c] + px,
                                          acc[t][r] + bis[c] + px * L2E);
        }
    }
    __syncthreads();
#pragma unroll
    for (int rr = 0; rr < 16; ++rr)
        Sfa[(base + rr) * 64 + lane] = stile[w][rr][lane];
}

// ---------------------------------------------------------------------------
// pt_gr8: R13's pt_gr7 minus the Wr->LDS staging. B-fragments come straight
// from the prebaked 16 KB WrT table (L1-hot). 512 thr = 8 waves, 2 groups/
// wave, 1024 blocks; readlane -> SGPR gather addressing; shift-invariant
// softmax; XCD-pinned swizzle. LDS = snf only (2.3 KB).
// ---------------------------------------------------------------------------
__global__ __launch_bounds__(512) void pt_gr8(
    const float* __restrict__ nxyz, const unsigned* __restrict__ Sfa,
    const short* __restrict__ WrT,
    const float* __restrict__ rg, const float* __restrict__ rb,
    const float* __restrict__ rm, const float* __restrict__ rv,
    const float* __restrict__ Wx,
    const float* __restrict__ xg, const float* __restrict__ xb,
    const float* __restrict__ xm, const float* __restrict__ xv,
    const int* __restrict__ gidx, const int* __restrict__ gcnt,
    float* __restrict__ out)
{
    __shared__ __align__(16) short snf[16][72];   // softmax outputs [group][ch]

    const int tid = threadIdx.x, lane = tid & 63, w = tid >> 6;
    const int row16 = lane & 15, kg = lane >> 4;
    // bijective XCD-pinning swizzle: xcd = blk%8 serves batch (blk%8)>>1
    const int i = blockIdx.x;                     // 0..1023
    const int b = (i & 7) >> 1;
    const int j = ((i >> 3) << 1) | (i & 1);      // 0..255
    const long long gbase = (long long)b * Mc + j * 16;

    // both groups' neighbor lists in one coalesced 64-int load (wave-local)
    const int nv = gidx[(gbase + 2 * w) * 32 + lane];

    // per-lane channel coeffs (channel = lane) + per-group constants
    const float xs = xg[lane] * rsqrtf(xv[lane] + EPSc);
    const float w0 = Wx[lane] * xs, w1 = Wx[64 + lane] * xs, w2 = Wx[128 + lane] * xs;
    const float P = xb[lane] - xm[lane] * xs;
    const float* nx = nxyz + (gbase + 2 * w) * 3;  // 6 floats = both groups
    const float QA = P - fmaf(nx[0], w0, fmaf(nx[1], w1, nx[2] * w2));
    const float QB = P - fmaf(nx[3], w0, fmaf(nx[4], w1, nx[5] * w2));

    // refine B-fragments straight from prebaked table (L1-hot 16 KB)
    const bf16x8 bf0 = *(const bf16x8*)(WrT + (16 * w + row16) * 64 + kg * 8);
    const bf16x8 bf1 = *(const bf16x8*)(WrT + (16 * w + row16) * 64 + 32 + kg * 8);

    const unsigned* sbase = Sfa + (long long)b * (Nc * 64) + lane;
    float ssA = 0.f, acA = 0.f, ssB = 0.f, acB = 0.f;
#pragma unroll
    for (int k = 0; k < Kc; ++k) {
        const int nA = __builtin_amdgcn_readlane(nv, k);        // SGPR index
        const int nB = __builtin_amdgcn_readlane(nv, 32 + k);
        const unsigned dA = sbase[nA << 6];        // SALU-addressed 256B gather
        const unsigned dB = sbase[nB << 6];
        // shift-invariance: u = exp2(hi) (Q cancels in the ratio)
        const float uA = __builtin_amdgcn_exp2f(__uint_as_float(dA & 0xffff0000u));
        const float uB = __builtin_amdgcn_exp2f(__uint_as_float(dB & 0xffff0000u));
        const float aA = __uint_as_float(dA << 16);
        const float aB = __uint_as_float(dB << 16);
        ssA += uA; acA = fmaf(uA, aA, acA);
        ssB += uB; acB = fmaf(uB, aB, acB);
    }
    snf[2 * w][lane]     = f2bf(fmaf(acA, __builtin_amdgcn_rcpf(ssA), QA));
    snf[2 * w + 1][lane] = f2bf(fmaf(acB, __builtin_amdgcn_rcpf(ssB), QB));
    __syncthreads();

    // refine MFMA: A = snf (16 rows), B = WrT col-tile w
    const bf16x8 af0 = *(const bf16x8*)&snf[row16][kg * 8];
    const bf16x8 af1 = *(const bf16x8*)&snf[row16][32 + kg * 8];
    f32x4 z = {0.f, 0.f, 0.f, 0.f};
    z = __builtin_amdgcn_mfma_f32_16x16x32_bf16(af0, bf0, z, 0, 0, 0);
    z = __builtin_amdgcn_mfma_f32_16x16x32_bf16(af1, bf1, z, 0, 0, 0);

    // epilogue: BN+ReLU+mask; per-lane channel cc fixed -> scale in registers
    const int4 c4 = *(const int4*)(gcnt + gbase + kg * 4);
    const int cc = 16 * w + row16;
    const float sr = rg[cc] * rsqrtf(rv[cc] + EPSc);
    const float bb = rb[cc] - rm[cc] * sr;
    float* orow = out + (gbase + kg * 4) * 128 + cc;
    __builtin_nontemporal_store(fmaxf(z[0] + bb, 0.f) * (c4.x > 0 ? 1.f : 0.f), orow);
    __builtin_nontemporal_store(fmaxf(z[1] + bb, 0.f) * (c4.y > 0 ? 1.f : 0.f), orow + 128);
    __builtin_nontemporal_store(fmaxf(z[2] + bb, 0.f) * (c4.z > 0 ? 1.f : 0.f), orow + 256);
    __builtin_nontemporal_store(fmaxf(z[3] + bb, 0.f) * (c4.w > 0 ? 1.f : 0.f), orow + 384);
}

extern "C" void kernel_launch(void* const* d_in, const int* in_sizes, int n_in,
                              void* d_out, int out_size, void* d_ws, size_t ws_size,
                              hipStream_t stream)
{
    const float* xyz  = (const float*)d_in[0];
    const float* nxyz = (const float*)d_in[1];
    const float* feats = (const float*)d_in[2];
    const float* Wf = (const float*)d_in[3];
    const float* fg = (const float*)d_in[4];
    const float* fb = (const float*)d_in[5];
    const float* fm = (const float*)d_in[6];
    const float* fv = (const float*)d_in[7];
    const float* Wa = (const float*)d_in[8];
    const float* ag = (const float*)d_in[9];
    const float* ab = (const float*)d_in[10];
    const float* am = (const float*)d_in[11];
    const float* av = (const float*)d_in[12];
    const float* Wx = (const float*)d_in[13];
    const float* xg = (const float*)d_in[14];
    const float* xb = (const float*)d_in[15];
    const float* xm = (const float*)d_in[16];
    const float* xv = (const float*)d_in[17];
    const float* Wr = (const float*)d_in[18];
    const float* rg = (const float*)d_in[19];
    const float* rb = (const float*)d_in[20];
    const float* rm = (const float*)d_in[21];
    const float* rv = (const float*)d_in[22];
    const int* gidx = (const int*)d_in[23];
    const int* gcnt = (const int*)d_in[24];
    float* out = (float*)d_out;

    char* ws = (char*)d_ws;
    unsigned* Sfa = (unsigned*)ws;                       // 16 MiB packed bf16 pairs
    short* WrT = (short*)(ws + (size_t)Bc * Nc * 64 * 4);  // 16 KB prebaked refine W

    pt_enc<<<dim3(1028), dim3(256), 0, stream>>>(
        feats, xyz, Wf, Wa, Wx,
        fg, fb, fm, fv, ag, ab, am, av, xg, xb, xm, xv,
        Wr, rg, rv, Sfa, WrT);
    pt_gr8<<<dim3((Bc * Mc) / 16), dim3(512), 0, stream>>>(
        nxyz, Sfa, WrT, rg, rb, rm, rv, Wx, xg, xb, xm, xv,
        gidx, gcnt, out);
}

// Round 17
// 28.803 us; speedup vs baseline: 1.1506x; 1.0720x over previous
//
#include <hip/hip_runtime.h>
#include <hip/hip_bf16.h>

constexpr int Bc = 4, Nc = 16384, Mc = 4096, Kc = 32;
constexpr float EPSc = 1e-5f;
constexpr float L2E = 1.4426950408889634f;   // log2(e)

using bf16x8 = __attribute__((ext_vector_type(8))) short;   // 8 bf16 (4 VGPRs)
using f32x4  = __attribute__((ext_vector_type(4))) float;   // 4 fp32

// HW bf16 converts (v_cvt_pk_bf16_f32, RNE)
__device__ inline short f2bf(float x) {
    union { __hip_bfloat16 h; short s; } cv;
    cv.h = __float2bfloat16(x);
    return cv.s;
}
__device__ inline unsigned pk2(float lo, float hi) {   // low16=bf16(lo), high16=bf16(hi)
    union { __hip_bfloat162 h2; unsigned u; } cv;
    cv.h2 = __float22bfloat162_rn(make_float2(lo, hi));
    return cv.u;
}

// ---------------------------------------------------------------------------
// pt_enc — byte-identical to R13 (28.65 µs anchor): MFMA encoder, xyz term
// folded, XCD-pair pinned swizzle matching gr, LDS-transposed coalesced C-write.
// ---------------------------------------------------------------------------
__global__ __launch_bounds__(256) void pt_enc(
    const float* __restrict__ feats, const float* __restrict__ xyz,
    const float* __restrict__ Wf, const float* __restrict__ Wa,
    const float* __restrict__ Wx,
    const float* __restrict__ fg, const float* __restrict__ fb,
    const float* __restrict__ fm, const float* __restrict__ fv,
    const float* __restrict__ ag, const float* __restrict__ ab,
    const float* __restrict__ am, const float* __restrict__ av,
    const float* __restrict__ xg, const float* __restrict__ xb,
    const float* __restrict__ xm, const float* __restrict__ xv,
    unsigned* __restrict__ Sfa)
{
    __shared__ __align__(16) short WT[128][72];   // [col][k]
    __shared__ unsigned stile[4][16][68];         // transpose tile per wave
    __shared__ float  sx[64][3];                  // block's 64 points' xyz
    __shared__ float4 scw[64];                    // per-channel {w0,w1,w2,-}
    __shared__ float  bis[128];

    const int tid = threadIdx.x, lane = tid & 63, w = tid >> 6;
    const int row16 = lane & 15, kg = lane >> 4;
    // bijective XCD-pinning swizzle: xcd=blk%8 -> batch (blk%8)>>1
    const int i = blockIdx.x;                     // 0..1023
    const int b = (i & 7) >> 1;
    const int j = ((i >> 3) << 1) | (i & 1);      // 0..255 tile within batch
    const long long row0 = ((long long)b * 256 + j) * 64;

    if (tid < 192) ((float*)sx)[tid] = xyz[row0 * 3 + tid];
    if (tid < 64) {
        const float xs = xg[tid] * rsqrtf(xv[tid] + EPSc);
        scw[tid] = make_float4(Wx[tid] * xs, Wx[64 + tid] * xs,
                               Wx[128 + tid] * xs, 0.f);
    }
    if (tid < 128) {
        const int c = tid & 63;
        const float g  = (tid < 64) ? fg[c] : ag[c];
        const float v  = (tid < 64) ? fv[c] : av[c];
        const float bb = (tid < 64) ? fb[c] : ab[c];
        const float mm = (tid < 64) ? fm[c] : am[c];
        const float s = g * rsqrtf(v + EPSc);
        bis[tid] = (tid < 64) ? (bb - mm * s) * L2E : (bb - mm * s);
    }
    {   // WT staging: thread owns channel c = tid&63 for both planes
        const int c = tid & 63, k0 = tid >> 6;
        const float sf = fg[c] * rsqrtf(fv[c] + EPSc) * L2E;
        const float sa = ag[c] * rsqrtf(av[c] + EPSc);
#pragma unroll
        for (int it = 0; it < 16; ++it) {
            const int k = k0 + 4 * it;
            WT[c][k]      = f2bf(Wf[k * 64 + c] * sf);
            WT[64 + c][k] = f2bf(Wa[k * 64 + c] * sa);
        }
    }
    __syncthreads();

    bf16x8 bfr[8][2];
#pragma unroll
    for (int t = 0; t < 8; ++t)
#pragma unroll
        for (int h = 0; h < 2; ++h)
            bfr[t][h] = *(const bf16x8*)&WT[16 * t + row16][32 * h + kg * 8];

    const long long base = row0 + w * 16;
    const float* arow = feats + (base + row16) * 64 + kg * 8;
    const float4 v0 = *(const float4*)(arow + 0);
    const float4 v1 = *(const float4*)(arow + 4);
    const float4 v2 = *(const float4*)(arow + 32);
    const float4 v3 = *(const float4*)(arow + 36);
    union { unsigned u[4]; bf16x8 v; } A0, A1;    // HW cvt_pk pairs
    A0.u[0] = pk2(v0.x, v0.y); A0.u[1] = pk2(v0.z, v0.w);
    A0.u[2] = pk2(v1.x, v1.y); A0.u[3] = pk2(v1.z, v1.w);
    A1.u[0] = pk2(v2.x, v2.y); A1.u[1] = pk2(v2.z, v2.w);
    A1.u[2] = pk2(v3.x, v3.y); A1.u[3] = pk2(v3.z, v3.w);

    f32x4 acc[8];
#pragma unroll
    for (int t = 0; t < 8; ++t) {
        f32x4 z = {0.f, 0.f, 0.f, 0.f};
        z = __builtin_amdgcn_mfma_f32_16x16x32_bf16(A0.v, bfr[t][0], z, 0, 0, 0);
        z = __builtin_amdgcn_mfma_f32_16x16x32_bf16(A1.v, bfr[t][1], z, 0, 0, 0);
        acc[t] = z;
    }

    float4 cwt[4];
#pragma unroll
    for (int t = 0; t < 4; ++t)
        cwt[t] = scw[16 * t + row16];

    const int lrow = w * 16 + kg * 4;
    // C/D layout: row=(lane>>4)*4+reg, col=lane&15 -> LDS tile -> coalesced
#pragma unroll
    for (int r = 0; r < 4; ++r) {
        const float x0 = sx[lrow + r][0], x1 = sx[lrow + r][1], x2 = sx[lrow + r][2];
#pragma unroll
        for (int t = 0; t < 4; ++t) {
            const int c = 16 * t + row16;
            const float px = fmaf(x0, cwt[t].x, fmaf(x1, cwt[t].y, x2 * cwt[t].z));
            // low16 = attn plane, high16 = feat plane (exp2 domain)
            stile[w][kg * 4 + r][c] = pk2(acc[t + 4][r] + bis[64 + c] + px,
                                          acc[t][r] + bis[c] + px * L2E);
        }
    }
    __syncthreads();
#pragma unroll
    for (int rr = 0; rr < 16; ++rr)
        Sfa[(base + rr) * 64 + lane] = stile[w][rr][lane];
}

// ---------------------------------------------------------------------------
// pt_gr9: R13's pt_gr7 with 4 groups/wave (32/block, 512 blocks).
// Halves chip-wide WT staging + block overhead; doubles in-flight gathers.
// readlane -> SGPR gather addressing; shift-invariant softmax; XCD pinning.
// ---------------------------------------------------------------------------
__global__ __launch_bounds__(512) void pt_gr9(
    const float* __restrict__ nxyz, const unsigned* __restrict__ Sfa,
    const float* __restrict__ Wr,
    const float* __restrict__ rg, const float* __restrict__ rb,
    const float* __restrict__ rm, const float* __restrict__ rv,
    const float* __restrict__ Wx,
    const float* __restrict__ xg, const float* __restrict__ xb,
    const float* __restrict__ xm, const float* __restrict__ xv,
    const int* __restrict__ gidx, const int* __restrict__ gcnt,
    float* __restrict__ out)
{
    __shared__ __align__(16) short WT[128][72];   // refine weights [col][k]
    __shared__ __align__(16) short snf[32][72];   // softmax outputs [group][ch]

    const int tid = threadIdx.x, lane = tid & 63, w = tid >> 6;
    const int row16 = lane & 15, kg = lane >> 4;
    // bijective XCD-pinning swizzle: xcd = blk%8 serves batch (blk%8)>>1
    const int i = blockIdx.x;                     // 0..511
    const int b = (i & 7) >> 1;
    const int j = ((i >> 3) << 1) | (i & 1);      // 0..127
    const long long gbase = (long long)b * Mc + j * 32;

    // 4 groups/wave: two coalesced 64-int neighbor-list loads
    const int g0 = 4 * w;
    const int nv0 = gidx[(gbase + g0) * 32 + lane];       // groups g0, g0+1
    const int nv1 = gidx[(gbase + g0 + 2) * 32 + lane];   // groups g0+2, g0+3

    {   // WT staging: thread owns channel c = tid&127 (scale in registers)
        const int c = tid & 127, k0 = tid >> 7;
        const float sr = rg[c] * rsqrtf(rv[c] + EPSc);
#pragma unroll
        for (int it = 0; it < 16; ++it) {
            const int k = k0 + 4 * it;
            WT[c][k] = f2bf(Wr[k * 128 + c] * sr);
        }
    }

    // per-lane channel coeffs (channel = lane) + per-group constants
    const float xs = xg[lane] * rsqrtf(xv[lane] + EPSc);
    const float w0 = Wx[lane] * xs, w1 = Wx[64 + lane] * xs, w2 = Wx[128 + lane] * xs;
    const float P = xb[lane] - xm[lane] * xs;
    const float* nx = nxyz + (gbase + g0) * 3;    // 12 floats = 4 groups
    const float QA = P - fmaf(nx[0], w0, fmaf(nx[1],  w1, nx[2]  * w2));
    const float QB = P - fmaf(nx[3], w0, fmaf(nx[4],  w1, nx[5]  * w2));
    const float QC = P - fmaf(nx[6], w0, fmaf(nx[7],  w1, nx[8]  * w2));
    const float QD = P - fmaf(nx[9], w0, fmaf(nx[10], w1, nx[11] * w2));

    const unsigned* sbase = Sfa + (long long)b * (Nc * 64) + lane;
    float ssA = 0.f, acA = 0.f, ssB = 0.f, acB = 0.f;
    float ssC = 0.f, acC = 0.f, ssD = 0.f, acD = 0.f;
#pragma unroll
    for (int k = 0; k < Kc; ++k) {
        const int nA = __builtin_amdgcn_readlane(nv0, k);
        const int nB = __builtin_amdgcn_readlane(nv0, 32 + k);
        const int nC = __builtin_amdgcn_readlane(nv1, k);
        const int nD = __builtin_amdgcn_readlane(nv1, 32 + k);
        const unsigned dA = sbase[nA << 6];        // SALU-addressed 256B gathers
        const unsigned dB = sbase[nB << 6];
        const unsigned dC = sbase[nC << 6];
        const unsigned dD = sbase[nD << 6];
        const float uA = __builtin_amdgcn_exp2f(__uint_as_float(dA & 0xffff0000u));
        const float uB = __builtin_amdgcn_exp2f(__uint_as_float(dB & 0xffff0000u));
        const float uC = __builtin_amdgcn_exp2f(__uint_as_float(dC & 0xffff0000u));
        const float uD = __builtin_amdgcn_exp2f(__uint_as_float(dD & 0xffff0000u));
        ssA += uA; acA = fmaf(uA, __uint_as_float(dA << 16), acA);
        ssB += uB; acB = fmaf(uB, __uint_as_float(dB << 16), acB);
        ssC += uC; acC = fmaf(uC, __uint_as_float(dC << 16), acC);
        ssD += uD; acD = fmaf(uD, __uint_as_float(dD << 16), acD);
    }
    snf[g0 + 0][lane] = f2bf(fmaf(acA, __builtin_amdgcn_rcpf(ssA), QA));
    snf[g0 + 1][lane] = f2bf(fmaf(acB, __builtin_amdgcn_rcpf(ssB), QB));
    snf[g0 + 2][lane] = f2bf(fmaf(acC, __builtin_amdgcn_rcpf(ssC), QC));
    snf[g0 + 3][lane] = f2bf(fmaf(acD, __builtin_amdgcn_rcpf(ssD), QD));
    __syncthreads();

    // refine MFMA: A = snf rows 0-15 and 16-31, B = WT col-tile w
    const bf16x8 bf0 = *(const bf16x8*)&WT[16 * w + row16][kg * 8];
    const bf16x8 bf1 = *(const bf16x8*)&WT[16 * w + row16][32 + kg * 8];
    const bf16x8 a00 = *(const bf16x8*)&snf[row16][kg * 8];
    const bf16x8 a01 = *(const bf16x8*)&snf[row16][32 + kg * 8];
    const bf16x8 a10 = *(const bf16x8*)&snf[16 + row16][kg * 8];
    const bf16x8 a11 = *(const bf16x8*)&snf[16 + row16][32 + kg * 8];
    f32x4 z0 = {0.f, 0.f, 0.f, 0.f}, z1 = {0.f, 0.f, 0.f, 0.f};
    z0 = __builtin_amdgcn_mfma_f32_16x16x32_bf16(a00, bf0, z0, 0, 0, 0);
    z0 = __builtin_amdgcn_mfma_f32_16x16x32_bf16(a01, bf1, z0, 0, 0, 0);
    z1 = __builtin_amdgcn_mfma_f32_16x16x32_bf16(a10, bf0, z1, 0, 0, 0);
    z1 = __builtin_amdgcn_mfma_f32_16x16x32_bf16(a11, bf1, z1, 0, 0, 0);

    // epilogue: BN+ReLU+mask for both 16-row tiles
    const int cc = 16 * w + row16;
    const float sr = rg[cc] * rsqrtf(rv[cc] + EPSc);
    const float bb = rb[cc] - rm[cc] * sr;
    const int4 c40 = *(const int4*)(gcnt + gbase + kg * 4);
    const int4 c41 = *(const int4*)(gcnt + gbase + 16 + kg * 4);
    float* orow0 = out + (gbase + kg * 4) * 128 + cc;
    float* orow1 = out + (gbase + 16 + kg * 4) * 128 + cc;
    __builtin_nontemporal_store(fmaxf(z0[0] + bb, 0.f) * (c40.x > 0 ? 1.f : 0.f), orow0);
    __builtin_nontemporal_store(fmaxf(z0[1] + bb, 0.f) * (c40.y > 0 ? 1.f : 0.f), orow0 + 128);
    __builtin_nontemporal_store(fmaxf(z0[2] + bb, 0.f) * (c40.z > 0 ? 1.f : 0.f), orow0 + 256);
    __builtin_nontemporal_store(fmaxf(z0[3] + bb, 0.f) * (c40.w > 0 ? 1.f : 0.f), orow0 + 384);
    __builtin_nontemporal_store(fmaxf(z1[0] + bb, 0.f) * (c41.x > 0 ? 1.f : 0.f), orow1);
    __builtin_nontemporal_store(fmaxf(z1[1] + bb, 0.f) * (c41.y > 0 ? 1.f : 0.f), orow1 + 128);
    __builtin_nontemporal_store(fmaxf(z1[2] + bb, 0.f) * (c41.z > 0 ? 1.f : 0.f), orow1 + 256);
    __builtin_nontemporal_store(fmaxf(z1[3] + bb, 0.f) * (c41.w > 0 ? 1.f : 0.f), orow1 + 384);
}

extern "C" void kernel_launch(void* const* d_in, const int* in_sizes, int n_in,
                              void* d_out, int out_size, void* d_ws, size_t ws_size,
                              hipStream_t stream)
{
    const float* xyz  = (const float*)d_in[0];
    const float* nxyz = (const float*)d_in[1];
    const float* feats = (const float*)d_in[2];
    const float* Wf = (const float*)d_in[3];
    const float* fg = (const float*)d_in[4];
    const float* fb = (const float*)d_in[5];
    const float* fm = (const float*)d_in[6];
    const float* fv = (const float*)d_in[7];
    const float* Wa = (const float*)d_in[8];
    const float* ag = (const float*)d_in[9];
    const float* ab = (const float*)d_in[10];
    const float* am = (const float*)d_in[11];
    const float* av = (const float*)d_in[12];
    const float* Wx = (const float*)d_in[13];
    const float* xg = (const float*)d_in[14];
    const float* xb = (const float*)d_in[15];
    const float* xm = (const float*)d_in[16];
    const float* xv = (const float*)d_in[17];
    const float* Wr = (const float*)d_in[18];
    const float* rg = (const float*)d_in[19];
    const float* rb = (const float*)d_in[20];
    const float* rm = (const float*)d_in[21];
    const float* rv = (const float*)d_in[22];
    const int* gidx = (const int*)d_in[23];
    const int* gcnt = (const int*)d_in[24];
    float* out = (float*)d_out;

    unsigned* Sfa = (unsigned*)d_ws;   // B*N*64 dwords = 16 MiB packed bf16 pairs

    pt_enc<<<dim3(Bc * Nc / 64), dim3(256), 0, stream>>>(
        feats, xyz, Wf, Wa, Wx,
        fg, fb, fm, fv, ag, ab, am, av, xg, xb, xm, xv, Sfa);
    pt_gr9<<<dim3((Bc * Mc) / 32), dim3(512), 0, stream>>>(
        nxyz, Sfa, Wr, rg, rb, rm, rv, Wx, xg, xb, xm, xv,
        gidx, gcnt, out);
}

// Round 18
// 28.629 us; speedup vs baseline: 1.1575x; 1.0061x over previous
//
#include <hip/hip_runtime.h>
#include <hip/hip_bf16.h>

constexpr int Bc = 4, Nc = 16384, Mc = 4096, Kc = 32;
constexpr float EPSc = 1e-5f;
constexpr float L2E = 1.4426950408889634f;   // log2(e)

using bf16x8 = __attribute__((ext_vector_type(8))) short;   // 8 bf16 (4 VGPRs)
using f32x4  = __attribute__((ext_vector_type(4))) float;   // 4 fp32

// HW bf16 converts (v_cvt_pk_bf16_f32, RNE)
__device__ inline short f2bf(float x) {
    union { __hip_bfloat16 h; short s; } cv;
    cv.h = __float2bfloat16(x);
    return cv.s;
}
__device__ inline unsigned pk2(float lo, float hi) {   // low16=bf16(lo), high16=bf16(hi)
    union { __hip_bfloat162 h2; unsigned u; } cv;
    cv.h2 = __float22bfloat162_rn(make_float2(lo, hi));
    return cv.u;
}

// ---------------------------------------------------------------------------
// pt_enc — byte-identical to R13 (28.65 µs anchor): MFMA encoder, xyz term
// folded, XCD-pair pinned swizzle matching gr, LDS-transposed coalesced C-write.
// ---------------------------------------------------------------------------
__global__ __launch_bounds__(256) void pt_enc(
    const float* __restrict__ feats, const float* __restrict__ xyz,
    const float* __restrict__ Wf, const float* __restrict__ Wa,
    const float* __restrict__ Wx,
    const float* __restrict__ fg, const float* __restrict__ fb,
    const float* __restrict__ fm, const float* __restrict__ fv,
    const float* __restrict__ ag, const float* __restrict__ ab,
    const float* __restrict__ am, const float* __restrict__ av,
    const float* __restrict__ xg, const float* __restrict__ xb,
    const float* __restrict__ xm, const float* __restrict__ xv,
    unsigned* __restrict__ Sfa)
{
    __shared__ __align__(16) short WT[128][72];   // [col][k]
    __shared__ unsigned stile[4][16][68];         // transpose tile per wave
    __shared__ float  sx[64][3];                  // block's 64 points' xyz
    __shared__ float4 scw[64];                    // per-channel {w0,w1,w2,-}
    __shared__ float  bis[128];

    const int tid = threadIdx.x, lane = tid & 63, w = tid >> 6;
    const int row16 = lane & 15, kg = lane >> 4;
    // bijective XCD-pinning swizzle: xcd=blk%8 -> batch (blk%8)>>1
    const int i = blockIdx.x;                     // 0..1023
    const int b = (i & 7) >> 1;
    const int j = ((i >> 3) << 1) | (i & 1);      // 0..255 tile within batch
    const long long row0 = ((long long)b * 256 + j) * 64;

    if (tid < 192) ((float*)sx)[tid] = xyz[row0 * 3 + tid];
    if (tid < 64) {
        const float xs = xg[tid] * rsqrtf(xv[tid] + EPSc);
        scw[tid] = make_float4(Wx[tid] * xs, Wx[64 + tid] * xs,
                               Wx[128 + tid] * xs, 0.f);
    }
    if (tid < 128) {
        const int c = tid & 63;
        const float g  = (tid < 64) ? fg[c] : ag[c];
        const float v  = (tid < 64) ? fv[c] : av[c];
        const float bb = (tid < 64) ? fb[c] : ab[c];
        const float mm = (tid < 64) ? fm[c] : am[c];
        const float s = g * rsqrtf(v + EPSc);
        bis[tid] = (tid < 64) ? (bb - mm * s) * L2E : (bb - mm * s);
    }
    {   // WT staging: thread owns channel c = tid&63 for both planes
        const int c = tid & 63, k0 = tid >> 6;
        const float sf = fg[c] * rsqrtf(fv[c] + EPSc) * L2E;
        const float sa = ag[c] * rsqrtf(av[c] + EPSc);
#pragma unroll
        for (int it = 0; it < 16; ++it) {
            const int k = k0 + 4 * it;
            WT[c][k]      = f2bf(Wf[k * 64 + c] * sf);
            WT[64 + c][k] = f2bf(Wa[k * 64 + c] * sa);
        }
    }
    __syncthreads();

    bf16x8 bfr[8][2];
#pragma unroll
    for (int t = 0; t < 8; ++t)
#pragma unroll
        for (int h = 0; h < 2; ++h)
            bfr[t][h] = *(const bf16x8*)&WT[16 * t + row16][32 * h + kg * 8];

    const long long base = row0 + w * 16;
    const float* arow = feats + (base + row16) * 64 + kg * 8;
    const float4 v0 = *(const float4*)(arow + 0);
    const float4 v1 = *(const float4*)(arow + 4);
    const float4 v2 = *(const float4*)(arow + 32);
    const float4 v3 = *(const float4*)(arow + 36);
    union { unsigned u[4]; bf16x8 v; } A0, A1;    // HW cvt_pk pairs
    A0.u[0] = pk2(v0.x, v0.y); A0.u[1] = pk2(v0.z, v0.w);
    A0.u[2] = pk2(v1.x, v1.y); A0.u[3] = pk2(v1.z, v1.w);
    A1.u[0] = pk2(v2.x, v2.y); A1.u[1] = pk2(v2.z, v2.w);
    A1.u[2] = pk2(v3.x, v3.y); A1.u[3] = pk2(v3.z, v3.w);

    f32x4 acc[8];
#pragma unroll
    for (int t = 0; t < 8; ++t) {
        f32x4 z = {0.f, 0.f, 0.f, 0.f};
        z = __builtin_amdgcn_mfma_f32_16x16x32_bf16(A0.v, bfr[t][0], z, 0, 0, 0);
        z = __builtin_amdgcn_mfma_f32_16x16x32_bf16(A1.v, bfr[t][1], z, 0, 0, 0);
        acc[t] = z;
    }

    float4 cwt[4];
#pragma unroll
    for (int t = 0; t < 4; ++t)
        cwt[t] = scw[16 * t + row16];

    const int lrow = w * 16 + kg * 4;
    // C/D layout: row=(lane>>4)*4+reg, col=lane&15 -> LDS tile -> coalesced
#pragma unroll
    for (int r = 0; r < 4; ++r) {
        const float x0 = sx[lrow + r][0], x1 = sx[lrow + r][1], x2 = sx[lrow + r][2];
#pragma unroll
        for (int t = 0; t < 4; ++t) {
            const int c = 16 * t + row16;
            const float px = fmaf(x0, cwt[t].x, fmaf(x1, cwt[t].y, x2 * cwt[t].z));
            // low16 = attn plane, high16 = feat plane (exp2 domain)
            stile[w][kg * 4 + r][c] = pk2(acc[t + 4][r] + bis[64 + c] + px,
                                          acc[t][r] + bis[c] + px * L2E);
        }
    }
    __syncthreads();
#pragma unroll
    for (int rr = 0; rr < 16; ++rr)
        Sfa[(base + rr) * 64 + lane] = stile[w][rr][lane];
}

// ---------------------------------------------------------------------------
// pt_gr10: R13's pt_gr7 with CHUNKED gather prefetch — 4 chunks of 8 k-steps;
// each chunk issues 16 gathers into static-indexed register arrays before
// consuming (16 loads in flight vs 2). Everything else identical to R13:
// 2 groups/wave, 1024 blocks, readlane->SGPR addressing, shift-invariant
// softmax, XCD-pinned swizzle, latency-hiding WT staging kept.
// ---------------------------------------------------------------------------
__global__ __launch_bounds__(512) void pt_gr10(
    const float* __restrict__ nxyz, const unsigned* __restrict__ Sfa,
    const float* __restrict__ Wr,
    const float* __restrict__ rg, const float* __restrict__ rb,
    const float* __restrict__ rm, const float* __restrict__ rv,
    const float* __restrict__ Wx,
    const float* __restrict__ xg, const float* __restrict__ xb,
    const float* __restrict__ xm, const float* __restrict__ xv,
    const int* __restrict__ gidx, const int* __restrict__ gcnt,
    float* __restrict__ out)
{
    __shared__ __align__(16) short WT[128][72];   // refine weights [col][k]
    __shared__ __align__(16) short snf[16][72];   // softmax outputs [group][ch]

    const int tid = threadIdx.x, lane = tid & 63, w = tid >> 6;
    const int row16 = lane & 15, kg = lane >> 4;
    // bijective XCD-pinning swizzle: xcd = blk%8 serves batch (blk%8)>>1
    const int i = blockIdx.x;                     // 0..1023
    const int b = (i & 7) >> 1;
    const int j = ((i >> 3) << 1) | (i & 1);      // 0..255
    const long long gbase = (long long)b * Mc + j * 16;

    // both groups' neighbor lists in one coalesced 64-int load (wave-local)
    const int nv = gidx[(gbase + 2 * w) * 32 + lane];

    {   // WT staging: thread owns channel c = tid&127 (scale in registers)
        const int c = tid & 127, k0 = tid >> 7;
        const float sr = rg[c] * rsqrtf(rv[c] + EPSc);
#pragma unroll
        for (int it = 0; it < 16; ++it) {
            const int k = k0 + 4 * it;
            WT[c][k] = f2bf(Wr[k * 128 + c] * sr);
        }
    }

    // per-lane channel coeffs (channel = lane) + per-group constants
    const float xs = xg[lane] * rsqrtf(xv[lane] + EPSc);
    const float w0 = Wx[lane] * xs, w1 = Wx[64 + lane] * xs, w2 = Wx[128 + lane] * xs;
    const float P = xb[lane] - xm[lane] * xs;
    const float* nx = nxyz + (gbase + 2 * w) * 3;  // 6 floats = both groups
    const float QA = P - fmaf(nx[0], w0, fmaf(nx[1], w1, nx[2] * w2));
    const float QB = P - fmaf(nx[3], w0, fmaf(nx[4], w1, nx[5] * w2));

    const unsigned* sbase = Sfa + (long long)b * (Nc * 64) + lane;
    float ssA = 0.f, acA = 0.f, ssB = 0.f, acB = 0.f;
#pragma unroll
    for (int kk = 0; kk < Kc; kk += 8) {
        unsigned dA[8], dB[8];                     // static-indexed -> registers
#pragma unroll
        for (int t = 0; t < 8; ++t) {
            const int nA = __builtin_amdgcn_readlane(nv, kk + t);
            const int nB = __builtin_amdgcn_readlane(nv, 32 + kk + t);
            dA[t] = sbase[nA << 6];                // 16 gathers in flight
            dB[t] = sbase[nB << 6];
        }
#pragma unroll
        for (int t = 0; t < 8; ++t) {
            // shift-invariance: u = exp2(hi) (Q cancels in the ratio)
            const float uA = __builtin_amdgcn_exp2f(__uint_as_float(dA[t] & 0xffff0000u));
            const float uB = __builtin_amdgcn_exp2f(__uint_as_float(dB[t] & 0xffff0000u));
            const float aA = __uint_as_float(dA[t] << 16);
            const float aB = __uint_as_float(dB[t] << 16);
            ssA += uA; acA = fmaf(uA, aA, acA);
            ssB += uB; acB = fmaf(uB, aB, acB);
        }
    }
    snf[2 * w][lane]     = f2bf(fmaf(acA, __builtin_amdgcn_rcpf(ssA), QA));
    snf[2 * w + 1][lane] = f2bf(fmaf(acB, __builtin_amdgcn_rcpf(ssB), QB));
    __syncthreads();

    // refine MFMA: A = snf (16 rows), B = WT col-tile w
    const bf16x8 af0 = *(const bf16x8*)&snf[row16][kg * 8];
    const bf16x8 af1 = *(const bf16x8*)&snf[row16][32 + kg * 8];
    const bf16x8 bf0 = *(const bf16x8*)&WT[16 * w + row16][kg * 8];
    const bf16x8 bf1 = *(const bf16x8*)&WT[16 * w + row16][32 + kg * 8];
    f32x4 z = {0.f, 0.f, 0.f, 0.f};
    z = __builtin_amdgcn_mfma_f32_16x16x32_bf16(af0, bf0, z, 0, 0, 0);
    z = __builtin_amdgcn_mfma_f32_16x16x32_bf16(af1, bf1, z, 0, 0, 0);

    // epilogue: BN+ReLU+mask; per-lane channel cc fixed -> scale in registers
    const int4 c4 = *(const int4*)(gcnt + gbase + kg * 4);
    const int cc = 16 * w + row16;
    const float sr = rg[cc] * rsqrtf(rv[cc] + EPSc);
    const float bb = rb[cc] - rm[cc] * sr;
    float* orow = out + (gbase + kg * 4) * 128 + cc;
    __builtin_nontemporal_store(fmaxf(z[0] + bb, 0.f) * (c4.x > 0 ? 1.f : 0.f), orow);
    __builtin_nontemporal_store(fmaxf(z[1] + bb, 0.f) * (c4.y > 0 ? 1.f : 0.f), orow + 128);
    __builtin_nontemporal_store(fmaxf(z[2] + bb, 0.f) * (c4.z > 0 ? 1.f : 0.f), orow + 256);
    __builtin_nontemporal_store(fmaxf(z[3] + bb, 0.f) * (c4.w > 0 ? 1.f : 0.f), orow + 384);
}

extern "C" void kernel_launch(void* const* d_in, const int* in_sizes, int n_in,
                              void* d_out, int out_size, void* d_ws, size_t ws_size,
                              hipStream_t stream)
{
    const float* xyz  = (const float*)d_in[0];
    const float* nxyz = (const float*)d_in[1];
    const float* feats = (const float*)d_in[2];
    const float* Wf = (const float*)d_in[3];
    const float* fg = (const float*)d_in[4];
    const float* fb = (const float*)d_in[5];
    const float* fm = (const float*)d_in[6];
    const float* fv = (const float*)d_in[7];
    const float* Wa = (const float*)d_in[8];
    const float* ag = (const float*)d_in[9];
    const float* ab = (const float*)d_in[10];
    const float* am = (const float*)d_in[11];
    const float* av = (const float*)d_in[12];
    const float* Wx = (const float*)d_in[13];
    const float* xg = (const float*)d_in[14];
    const float* xb = (const float*)d_in[15];
    const float* xm = (const float*)d_in[16];
    const float* xv = (const float*)d_in[17];
    const float* Wr = (const float*)d_in[18];
    const float* rg = (const float*)d_in[19];
    const float* rb = (const float*)d_in[20];
    const float* rm = (const float*)d_in[21];
    const float* rv = (const float*)d_in[22];
    const int* gidx = (const int*)d_in[23];
    const int* gcnt = (const int*)d_in[24];
    float* out = (float*)d_out;

    unsigned* Sfa = (unsigned*)d_ws;   // B*N*64 dwords = 16 MiB packed bf16 pairs

    pt_enc<<<dim3(Bc * Nc / 64), dim3(256), 0, stream>>>(
        feats, xyz, Wf, Wa, Wx,
        fg, fb, fm, fv, ag, ab, am, av, xg, xb, xm, xv, Sfa);
    pt_gr10<<<dim3((Bc * Mc) / 16), dim3(512), 0, stream>>>(
        nxyz, Sfa, Wr, rg, rb, rm, rv, Wx, xg, xb, xm, xv,
        gidx, gcnt, out);
}